// Round 20
// baseline (54.518 us; speedup 1.0000x reference)
//
#include <hip/hip_runtime.h>
#include <math.h>

#define NXg 512
#define NYg 512
#define NSEG (NXg * NYg)   // 262144 = 2^18
#define CCH 64
#define CAP 16             // total capacity per pillar (first + 15 ext)
#define ECAP 15            // ext slots per pillar
#define SLOTS 4            // points staged in LDS per pillar (k>4 -> global ext)
#define PSTR 5             // LDS point-slot stride
#define PPB 64             // pillars per tile
#define TPT 4              // tiles per block (grid-strided)
#define BN_EPS 1e-3f

// grid constants (f32, as in the reference arrays)
#define PCMINX (-51.2f)
#define PCMINY (-51.2f)
#define PCMINZ (-3.0f)
#define PCMAXX (51.2f)
#define PCMAXY (51.2f)
#define PCMAXZ (3.0f)
#define VOXX (0.2f)
#define VOXY (0.2f)
#define VOXZ (6.0f)

// f32-exact reciprocals (XLA fast-math computes (p-min)*(1/voxel) in f32).
#define RECIPX 5.0f
#define RECIPY 5.0f
#define RECIPZ (__uint_as_float(0x3E2AAAABu))   // (float)(1/6.0f)

// native vector type for nontemporal stores
typedef float nt_float4 __attribute__((ext_vector_type(4)));

__device__ __forceinline__ int calc_pid(float x, float y, float z) {
    bool in_range = (x >= PCMINX) && (x < PCMAXX) &&
                    (y >= PCMINY) && (y < PCMAXY) &&
                    (z >= PCMINZ) && (z < PCMAXZ);
    if (!in_range) return -1;
    int cx = (int)floorf((x - PCMINX) * RECIPX);
    int cy = (int)floorf((y - PCMINY) * RECIPY);
    int p = cy * NXg + cx;
    return (p >= 0 && p < NSEG) ? p : -1;
}

// K1: point 0 -> first[gp] (w = precomputed z-center offset);
// points 1..15 -> ext[gp*15 + slot-1].
__global__ void k1_bin(const float* __restrict__ pts, unsigned* __restrict__ cnt,
                       float4* __restrict__ first, float4* __restrict__ ext,
                       int B, int N) {
    int i = blockIdx.x * blockDim.x + threadIdx.x;
    if (i >= B * N) return;
    const float* p = pts + (size_t)i * 3;
    float x = p[0], y = p[1], z = p[2];
    int pd = calc_pid(x, y, z);
    if (pd < 0) return;
    int b = i / N;
    int g = b * NSEG + pd;
    unsigned slot = atomicAdd(&cnt[g], 1u);
    float cz = floorf((z - PCMINZ) * RECIPZ);
    float ctz = (cz + 0.5f) * VOXZ + PCMINZ;
    float4 e; e.x = x; e.y = y; e.z = z; e.w = z - ctz;   // zc precomputed
    if (slot == 0) first[g] = e;
    else if (slot < CAP) ext[(size_t)g * ECAP + (slot - 1)] = e;
}

// K4: r18 structure, grid-strided over TPT tiles per block (single variable:
// block setup + ramp amortized 4x; per-tile memory behavior identical).
__global__ void __launch_bounds__(256) k4_compute(
    const unsigned* __restrict__ cnt, const float4* __restrict__ first,
    const float4* __restrict__ ext,
    const float* __restrict__ W, const float* __restrict__ gamma,
    const float* __restrict__ beta, const float* __restrict__ rmean,
    const float* __restrict__ rvar, float* __restrict__ out, int ntiles) {
    __shared__ float pxs[PPB * PSTR];
    __shared__ float pys[PPB * PSTR];
    __shared__ float pzs[PPB * PSTR];
    __shared__ float pws[PPB * PSTR];
    __shared__ float mxs[PPB], mys[PPB], mzs[PPB];
    __shared__ int ks[PPB];
    __shared__ float tileb[CCH * 65];   // [c][p_local]

    int t = threadIdx.x;
    int lane = t & 63;
    int wave = t >> 6;

    // per-lane channel constants (amortized over TPT tiles)
    float w0 = W[0 * CCH + lane], w1 = W[1 * CCH + lane], w2 = W[2 * CCH + lane];
    float w3 = W[3 * CCH + lane], w4 = W[4 * CCH + lane], w5 = W[5 * CCH + lane];
    float w6 = W[6 * CCH + lane], w7 = W[7 * CCH + lane], w8 = W[8 * CCH + lane];
    float sc = gamma[lane] * (1.0f / sqrtf(rvar[lane] + BN_EPS));
    float shift = beta[lane] - rmean[lane] * sc;
    float Ac = (w0 + w3 + w6) * sc;
    float Bc = (w1 + w4 + w7) * sc;
    float Cc = (w2 + w5) * sc;
    float s3 = w3 * sc, s4 = w4 * sc, s5 = w5 * sc;
    float s6 = w6 * sc, s7 = w7 * sc, s8 = w8 * sc;

    for (int tile = (int)blockIdx.x; tile < ntiles; tile += (int)gridDim.x) {
        int gp0 = tile * PPB;

        // ---- phase 1: lane-per-pillar; cnt+first independent loads ----
        if (t < PPB) {
            int gp = gp0 + t;
            float4 f0 = first[gp];
            unsigned kc = cnt[gp];
            int k = (kc < CAP) ? (int)kc : CAP;
            ks[t] = k;
            float sx = 0.f, sy = 0.f, sz = 0.f;
            if (k > 0) {
                sx = f0.x; sy = f0.y; sz = f0.z;
                pxs[t * PSTR + 0] = f0.x;
                pys[t * PSTR + 0] = f0.y;
                pzs[t * PSTR + 0] = f0.z;
                pws[t * PSTR + 0] = f0.w;
                const float4* ex = ext + (size_t)gp * ECAP;
                for (int j = 1; j < k; ++j) {   // ~3% of pillars
                    float4 e = ex[j - 1];
                    if (j < SLOTS) {
                        pxs[t * PSTR + j] = e.x;
                        pys[t * PSTR + j] = e.y;
                        pzs[t * PSTR + j] = e.z;
                        pws[t * PSTR + j] = e.w;
                    }
                    sx += e.x; sy += e.y; sz += e.z;
                }
            }
            float fk = (k > 0) ? (float)k : 1.0f;
            mxs[t] = sx / fk; mys[t] = sy / fk; mzs[t] = sz / fk;
        }
        __syncthreads();

        // ---- phase 2: wave-per-pillar, lane = channel, folded PFN ----
        for (int it = 0; it < 16; ++it) {
            int ppl = wave * 16 + it;
            int k = ks[ppl];
            float acc = 0.0f;
            if (k > 0) {
                float mx = mxs[ppl], my = mys[ppl], mz = mzs[ppl];
                int pid = (gp0 + ppl) & (NSEG - 1);
                float ctx = ((float)(pid & (NXg - 1)) + 0.5f) * VOXX + PCMINX;
                float cty = ((float)(pid >> 9) + 0.5f) * VOXY + PCMINY;
                float D = shift;
                D = fmaf(-mx, s3, D); D = fmaf(-my, s4, D); D = fmaf(-mz, s5, D);
                D = fmaf(-ctx, s6, D); D = fmaf(-cty, s7, D);
                int kl = (k < SLOTS) ? k : SLOTS;
                for (int j = 0; j < kl; ++j) {
                    float x = pxs[ppl * PSTR + j];
                    float y = pys[ppl * PSTR + j];
                    float z = pzs[ppl * PSTR + j];
                    float zc = pws[ppl * PSTR + j];
                    float h = fmaf(x, Ac, fmaf(y, Bc, fmaf(z, Cc,
                                  fmaf(zc, s8, D))));
                    acc += fmaxf(h, 0.0f);
                }
                for (int j = SLOTS; j < k; ++j) {      // ~never taken
                    float4 e = ext[(size_t)(gp0 + ppl) * ECAP + (j - 1)];
                    float h = fmaf(e.x, Ac, fmaf(e.y, Bc, fmaf(e.z, Cc,
                                  fmaf(e.w, s8, D))));
                    acc += fmaxf(h, 0.0f);
                }
                acc /= (float)k;
            }
            tileb[lane * 65 + ppl] = acc;
        }
        __syncthreads();

        // ---- phase 3: nontemporal float4 write-out (64 rows x 16 float4) ----
        int b = gp0 >> 18;                 // NSEG = 2^18
        int pbatch = gp0 & (NSEG - 1);
        size_t obase = (size_t)b * CCH * NSEG + (size_t)pbatch;
        for (int jj = 0; jj < 4; ++jj) {
            int idx = jj * 256 + t;
            int c = idx >> 4;              // channel row 0..63
            int q = idx & 15;              // float4 within row
            nt_float4 v;
            v.x = tileb[c * 65 + q * 4 + 0];
            v.y = tileb[c * 65 + q * 4 + 1];
            v.z = tileb[c * 65 + q * 4 + 2];
            v.w = tileb[c * 65 + q * 4 + 3];
            __builtin_nontemporal_store(
                v, reinterpret_cast<nt_float4*>(out + obase + (size_t)c * NSEG + q * 4));
        }
        __syncthreads();   // tileb/staging reuse across grid-stride iterations
    }
}

extern "C" void kernel_launch(void* const* d_in, const int* in_sizes, int n_in,
                              void* d_out, int out_size, void* d_ws, size_t ws_size,
                              hipStream_t stream) {
    const float* points = (const float*)d_in[0];
    const float* W      = (const float*)d_in[1];
    const float* gamma  = (const float*)d_in[2];
    const float* beta   = (const float*)d_in[3];
    const float* rmean  = (const float*)d_in[4];
    const float* rvar   = (const float*)d_in[5];
    float* out = (float*)d_out;

    int B = out_size / (CCH * NSEG);          // 2
    int N = in_sizes[0] / (3 * B);            // 100000
    int BN = B * NSEG;                        // 524288
    int total_pts = B * N;

    // workspace: cnt [BN] u32 (2 MB) + first [BN] float4 (8.4 MB)
    //          + ext [BN*15] float4 (126 MB)
    unsigned* cnt = (unsigned*)d_ws;
    float4* first = (float4*)(cnt + BN);
    float4* ext   = first + BN;

    (void)hipMemsetAsync(cnt, 0, (size_t)BN * sizeof(unsigned), stream);

    int blk = 256;
    int grd_pts = (total_pts + blk - 1) / blk;
    k1_bin<<<grd_pts, blk, 0, stream>>>(points, cnt, first, ext, B, N);
    int ntiles = BN / PPB;                    // 8192
    k4_compute<<<ntiles / TPT, blk, 0, stream>>>(cnt, first, ext, W, gamma,
                                                 beta, rmean, rvar, out, ntiles);
}

// Round 21
// 53.515 us; speedup vs baseline: 1.0187x; 1.0187x over previous
//
#include <hip/hip_runtime.h>
#include <math.h>

#define NXg 512
#define NYg 512
#define NSEG (NXg * NYg)   // 262144 = 2^18
#define CCH 64
#define CAP 16             // total capacity per pillar (first + 15 ext)
#define ECAP 15            // ext slots per pillar
#define LSLOT 2            // point slots staged in LDS (j>=2 -> global ext, ~4%)
#define PPB 256            // pillars per block
#define BLK 1024
#define TSTR 257           // tileb row stride (257 % 32 == 1 -> conflict-free)
#define BN_EPS 1e-3f

// grid constants (f32, as in the reference arrays)
#define PCMINX (-51.2f)
#define PCMINY (-51.2f)
#define PCMINZ (-3.0f)
#define PCMAXX (51.2f)
#define PCMAXY (51.2f)
#define PCMAXZ (3.0f)
#define VOXX (0.2f)
#define VOXY (0.2f)
#define VOXZ (6.0f)

// f32-exact reciprocals (XLA fast-math computes (p-min)*(1/voxel) in f32).
#define RECIPX 5.0f
#define RECIPY 5.0f
#define RECIPZ (__uint_as_float(0x3E2AAAABu))   // (float)(1/6.0f)

// native vector type for nontemporal stores
typedef float nt_float4 __attribute__((ext_vector_type(4)));

__device__ __forceinline__ int calc_pid(float x, float y, float z) {
    bool in_range = (x >= PCMINX) && (x < PCMAXX) &&
                    (y >= PCMINY) && (y < PCMAXY) &&
                    (z >= PCMINZ) && (z < PCMAXZ);
    if (!in_range) return -1;
    int cx = (int)floorf((x - PCMINX) * RECIPX);
    int cy = (int)floorf((y - PCMINY) * RECIPY);
    int p = cy * NXg + cx;
    return (p >= 0 && p < NSEG) ? p : -1;
}

// K1: point 0 -> first[gp] (w = precomputed z-center offset);
// points 1..15 -> ext[gp*15 + slot-1].
__global__ void k1_bin(const float* __restrict__ pts, unsigned* __restrict__ cnt,
                       float4* __restrict__ first, float4* __restrict__ ext,
                       int B, int N) {
    int i = blockIdx.x * blockDim.x + threadIdx.x;
    if (i >= B * N) return;
    const float* p = pts + (size_t)i * 3;
    float x = p[0], y = p[1], z = p[2];
    int pd = calc_pid(x, y, z);
    if (pd < 0) return;
    int b = i / N;
    int g = b * NSEG + pd;
    unsigned slot = atomicAdd(&cnt[g], 1u);
    float cz = floorf((z - PCMINZ) * RECIPZ);
    float ctz = (cz + 0.5f) * VOXZ + PCMINZ;
    float4 e; e.x = x; e.y = y; e.z = z; e.w = z - ctz;   // zc precomputed
    if (slot == 0) first[g] = e;
    else if (slot < CAP) ext[(size_t)g * ECAP + (slot - 1)] = e;
}

// K4: 256 pillars / 1024-thread block; 2 blocks/CU (32 waves/CU, max).
// Phase 1: slot-parallel gather (thread = pillar x slot, 4-lane shfl mean).
// Phase 2: wave-per-pillar (16 waves x 16 pillars), lane = channel, folded PFN.
// Phase 3: one WAVE per channel row -> 1KB-contiguous nt stores.
__global__ void __launch_bounds__(BLK, 8) k4_compute(
    const unsigned* __restrict__ cnt, const float4* __restrict__ first,
    const float4* __restrict__ ext,
    const float* __restrict__ W, const float* __restrict__ gamma,
    const float* __restrict__ beta, const float* __restrict__ rmean,
    const float* __restrict__ rvar, float* __restrict__ out) {
    __shared__ float pxs[LSLOT][PPB];
    __shared__ float pys[LSLOT][PPB];
    __shared__ float pzs[LSLOT][PPB];
    __shared__ float pws[LSLOT][PPB];
    __shared__ float mxs[PPB], mys[PPB], mzs[PPB];
    __shared__ int ks[PPB];
    __shared__ float tileb[CCH * TSTR];   // [c][p_local]

    int t = threadIdx.x;
    int lane = t & 63;
    int wave = t >> 6;                 // 0..15
    int gp0 = (int)blockIdx.x * PPB;

    // per-lane channel constants (lane = channel in phase 2)
    float w0 = W[0 * CCH + lane], w1 = W[1 * CCH + lane], w2 = W[2 * CCH + lane];
    float w3 = W[3 * CCH + lane], w4 = W[4 * CCH + lane], w5 = W[5 * CCH + lane];
    float w6 = W[6 * CCH + lane], w7 = W[7 * CCH + lane], w8 = W[8 * CCH + lane];
    float sc = gamma[lane] * (1.0f / sqrtf(rvar[lane] + BN_EPS));
    float shift = beta[lane] - rmean[lane] * sc;
    float Ac = (w0 + w3 + w6) * sc;
    float Bc = (w1 + w4 + w7) * sc;
    float Cc = (w2 + w5) * sc;
    float s3 = w3 * sc, s4 = w4 * sc, s5 = w5 * sc;
    float s6 = w6 * sc, s7 = w7 * sc, s8 = w8 * sc;

    // ---- phase 1: slot-parallel gather; thread = (pillar, slot) ----
    {
        int p = t >> 2;                // 0..255
        int s = t & 3;                 // 0..3
        int gp = gp0 + p;
        unsigned kc = cnt[gp];         // 4x redundant, L1 broadcast
        int k = (kc < CAP) ? (int)kc : CAP;
        float4 e;
        bool valid;
        if (s == 0) { e = first[gp]; valid = (k > 0); }
        else { valid = (s < k); if (valid) e = ext[(size_t)gp * ECAP + (s - 1)]; }
        float px = valid ? e.x : 0.f;
        float py = valid ? e.y : 0.f;
        float pz = valid ? e.z : 0.f;
        if (valid && s < LSLOT) {
            pxs[s][p] = e.x; pys[s][p] = e.y; pzs[s][p] = e.z; pws[s][p] = e.w;
        }
        px += __shfl_xor(px, 1); py += __shfl_xor(py, 1); pz += __shfl_xor(pz, 1);
        px += __shfl_xor(px, 2); py += __shfl_xor(py, 2); pz += __shfl_xor(pz, 2);
        if (s == 0) {
            for (int j = 4; j < k; ++j) {   // ultra-rare tail
                float4 et = ext[(size_t)gp * ECAP + (j - 1)];
                px += et.x; py += et.y; pz += et.z;
            }
            ks[p] = k;
            float fk = (k > 0) ? (float)k : 1.0f;
            mxs[p] = px / fk; mys[p] = py / fk; mzs[p] = pz / fk;
        }
    }
    __syncthreads();

    // ---- phase 2: wave-per-pillar (16 waves x 16 pillars), lane = channel ----
    for (int it = 0; it < 16; ++it) {
        int ppl = wave * 16 + it;
        int k = ks[ppl];
        float acc = 0.0f;
        if (k > 0) {
            float mx = mxs[ppl], my = mys[ppl], mz = mzs[ppl];
            int pid = (gp0 + ppl) & (NSEG - 1);
            float ctx = ((float)(pid & (NXg - 1)) + 0.5f) * VOXX + PCMINX;
            float cty = ((float)(pid >> 9) + 0.5f) * VOXY + PCMINY;
            float D = shift;
            D = fmaf(-mx, s3, D); D = fmaf(-my, s4, D); D = fmaf(-mz, s5, D);
            D = fmaf(-ctx, s6, D); D = fmaf(-cty, s7, D);
            int kl = (k < LSLOT) ? k : LSLOT;
            for (int j = 0; j < kl; ++j) {
                float x = pxs[j][ppl];
                float y = pys[j][ppl];
                float z = pzs[j][ppl];
                float zc = pws[j][ppl];
                float h = fmaf(x, Ac, fmaf(y, Bc, fmaf(z, Cc, fmaf(zc, s8, D))));
                acc += fmaxf(h, 0.0f);
            }
            for (int j = LSLOT; j < k; ++j) {   // ~4% of occupied pillars
                float4 e = ext[(size_t)(gp0 + ppl) * ECAP + (j - 1)];
                float h = fmaf(e.x, Ac, fmaf(e.y, Bc, fmaf(e.z, Cc,
                              fmaf(e.w, s8, D))));
                acc += fmaxf(h, 0.0f);
            }
            acc /= (float)k;
        }
        tileb[lane * TSTR + ppl] = acc;
    }
    __syncthreads();

    // ---- phase 3: wave-per-channel-row nt stores (64 rows x 64 float4) ----
    // per wave-instruction: 64 lanes x 16B = 1KB CONTIGUOUS.
    int b = gp0 >> 18;                 // NSEG = 2^18
    int pbatch = gp0 & (NSEG - 1);
    size_t obase = (size_t)b * CCH * NSEG + (size_t)pbatch;
    for (int jj = 0; jj < 4; ++jj) {
        int idx = jj * BLK + t;        // 0..4095
        int c = idx >> 6;              // channel row 0..63
        int q = idx & 63;              // float4 within row
        nt_float4 v;
        v.x = tileb[c * TSTR + q * 4 + 0];
        v.y = tileb[c * TSTR + q * 4 + 1];
        v.z = tileb[c * TSTR + q * 4 + 2];
        v.w = tileb[c * TSTR + q * 4 + 3];
        __builtin_nontemporal_store(
            v, reinterpret_cast<nt_float4*>(out + obase + (size_t)c * NSEG + q * 4));
    }
}

extern "C" void kernel_launch(void* const* d_in, const int* in_sizes, int n_in,
                              void* d_out, int out_size, void* d_ws, size_t ws_size,
                              hipStream_t stream) {
    const float* points = (const float*)d_in[0];
    const float* W      = (const float*)d_in[1];
    const float* gamma  = (const float*)d_in[2];
    const float* beta   = (const float*)d_in[3];
    const float* rmean  = (const float*)d_in[4];
    const float* rvar   = (const float*)d_in[5];
    float* out = (float*)d_out;

    int B = out_size / (CCH * NSEG);          // 2
    int N = in_sizes[0] / (3 * B);            // 100000
    int BN = B * NSEG;                        // 524288
    int total_pts = B * N;

    // workspace: cnt [BN] u32 (2 MB) + first [BN] float4 (8.4 MB)
    //          + ext [BN*15] float4 (126 MB)
    unsigned* cnt = (unsigned*)d_ws;
    float4* first = (float4*)(cnt + BN);
    float4* ext   = first + BN;

    (void)hipMemsetAsync(cnt, 0, (size_t)BN * sizeof(unsigned), stream);

    int blk = 256;
    int grd_pts = (total_pts + blk - 1) / blk;
    k1_bin<<<grd_pts, blk, 0, stream>>>(points, cnt, first, ext, B, N);
    k4_compute<<<BN / PPB, BLK, 0, stream>>>(cnt, first, ext, W, gamma, beta,
                                             rmean, rvar, out);
}

// Round 23
// 46.914 us; speedup vs baseline: 1.1621x; 1.1407x over previous
//
#include <hip/hip_runtime.h>
#include <math.h>

#define NXg 512
#define NYg 512
#define NSEG (NXg * NYg)   // 262144 = 2^18
#define CCH 64
#define CAP 16             // total capacity per pillar (first + 15 ext)
#define ECAP 15            // ext slots per pillar
#define SLOTS 4            // points staged in LDS per pillar (k>4 -> global ext)
#define PSTR 5             // LDS point-slot stride
#define PPB 64             // pillars per tile
#define BN_EPS 1e-3f

// grid constants (f32, as in the reference arrays)
#define PCMINX (-51.2f)
#define PCMINY (-51.2f)
#define PCMINZ (-3.0f)
#define PCMAXX (51.2f)
#define PCMAXY (51.2f)
#define PCMAXZ (3.0f)
#define VOXX (0.2f)
#define VOXY (0.2f)
#define VOXZ (6.0f)

// f32-exact reciprocals (XLA fast-math computes (p-min)*(1/voxel) in f32).
#define RECIPX 5.0f
#define RECIPY 5.0f
#define RECIPZ (__uint_as_float(0x3E2AAAABu))   // (float)(1/6.0f)

// native vector type for nontemporal stores (HIP float4 is a class type,
// which __builtin_nontemporal_store rejects)
typedef float nt_float4 __attribute__((ext_vector_type(4)));

__device__ __forceinline__ int calc_pid(float x, float y, float z) {
    bool in_range = (x >= PCMINX) && (x < PCMAXX) &&
                    (y >= PCMINY) && (y < PCMAXY) &&
                    (z >= PCMINZ) && (z < PCMAXZ);
    if (!in_range) return -1;
    int cx = (int)floorf((x - PCMINX) * RECIPX);
    int cy = (int)floorf((y - PCMINY) * RECIPY);
    int p = cy * NXg + cx;
    return (p >= 0 && p < NSEG) ? p : -1;
}

// K1: point 0 of each pillar -> first[gp]; points 1..15 -> ext[gp*15 + slot-1].
__global__ void k1_bin(const float* __restrict__ pts, unsigned* __restrict__ cnt,
                       float4* __restrict__ first, float4* __restrict__ ext,
                       int B, int N) {
    int i = blockIdx.x * blockDim.x + threadIdx.x;
    if (i >= B * N) return;
    const float* p = pts + (size_t)i * 3;
    float x = p[0], y = p[1], z = p[2];
    int pd = calc_pid(x, y, z);
    if (pd < 0) return;
    int b = i / N;
    int g = b * NSEG + pd;
    unsigned slot = atomicAdd(&cnt[g], 1u);
    float4 e; e.x = x; e.y = y; e.z = z; e.w = 0.0f;
    if (slot == 0) first[g] = e;
    else if (slot < CAP) ext[(size_t)g * ECAP + (slot - 1)] = e;
}

// K4 (empirical optimum, r18): block = one 64-pillar tile.
// Phase 1: lane-per-pillar gather, cnt+first issued as independent loads;
// ext touched only for k>=2 (~3% of pillars). Phase 2: wave-per-pillar,
// lane-per-channel folded PFN (weights+BN collapsed into registers).
// Phase 3: LDS-transposed, nontemporal float4 canvas write (every output
// element written -> no out memset).
__global__ void __launch_bounds__(256) k4_compute(
    const unsigned* __restrict__ cnt, const float4* __restrict__ first,
    const float4* __restrict__ ext,
    const float* __restrict__ W, const float* __restrict__ gamma,
    const float* __restrict__ beta, const float* __restrict__ rmean,
    const float* __restrict__ rvar, float* __restrict__ out) {
    __shared__ float pxs[PPB * PSTR];
    __shared__ float pys[PPB * PSTR];
    __shared__ float pzs[PPB * PSTR];
    __shared__ float mxs[PPB], mys[PPB], mzs[PPB];
    __shared__ int ks[PPB];
    __shared__ float tileb[CCH * 65];   // [c][p_local]

    int t = threadIdx.x;
    int lane = t & 63;
    int wave = t >> 6;
    int gp0 = (int)blockIdx.x * PPB;

    // per-lane channel constants (coalesced, L2-hot)
    float w0 = W[0 * CCH + lane], w1 = W[1 * CCH + lane], w2 = W[2 * CCH + lane];
    float w3 = W[3 * CCH + lane], w4 = W[4 * CCH + lane], w5 = W[5 * CCH + lane];
    float w6 = W[6 * CCH + lane], w7 = W[7 * CCH + lane], w8 = W[8 * CCH + lane];
    float sc = gamma[lane] * (1.0f / sqrtf(rvar[lane] + BN_EPS));
    float shift = beta[lane] - rmean[lane] * sc;
    float Ac = (w0 + w3 + w6) * sc;
    float Bc = (w1 + w4 + w7) * sc;
    float Cc = (w2 + w5) * sc;
    float s3 = w3 * sc, s4 = w4 * sc, s5 = w5 * sc;
    float s6 = w6 * sc, s7 = w7 * sc, s8 = w8 * sc;

    // ---- phase 1: lane-per-pillar; cnt+first independent loads ----
    if (t < PPB) {
        int gp = gp0 + t;
        float4 f0 = first[gp];
        unsigned kc = cnt[gp];
        int k = (kc < CAP) ? (int)kc : CAP;
        ks[t] = k;
        float sx = 0.f, sy = 0.f, sz = 0.f;
        if (k > 0) {
            sx = f0.x; sy = f0.y; sz = f0.z;
            pxs[t * PSTR + 0] = f0.x;
            pys[t * PSTR + 0] = f0.y;
            pzs[t * PSTR + 0] = f0.z;
            const float4* ex = ext + (size_t)gp * ECAP;
            for (int j = 1; j < k; ++j) {   // ~3% of pillars
                float4 e = ex[j - 1];
                if (j < SLOTS) {
                    pxs[t * PSTR + j] = e.x;
                    pys[t * PSTR + j] = e.y;
                    pzs[t * PSTR + j] = e.z;
                }
                sx += e.x; sy += e.y; sz += e.z;
            }
        }
        float fk = (k > 0) ? (float)k : 1.0f;
        mxs[t] = sx / fk; mys[t] = sy / fk; mzs[t] = sz / fk;
    }
    __syncthreads();

    // ---- phase 2: wave-per-pillar, lane = channel, folded PFN ----
    for (int it = 0; it < 16; ++it) {
        int ppl = wave * 16 + it;
        int k = ks[ppl];
        float acc = 0.0f;
        if (k > 0) {
            float mx = mxs[ppl], my = mys[ppl], mz = mzs[ppl];
            int pid = (gp0 + ppl) & (NSEG - 1);
            float ctx = ((float)(pid & (NXg - 1)) + 0.5f) * VOXX + PCMINX;
            float cty = ((float)(pid >> 9) + 0.5f) * VOXY + PCMINY;
            float D = shift;
            D = fmaf(-mx, s3, D); D = fmaf(-my, s4, D); D = fmaf(-mz, s5, D);
            D = fmaf(-ctx, s6, D); D = fmaf(-cty, s7, D);
            int kl = (k < SLOTS) ? k : SLOTS;
            for (int j = 0; j < kl; ++j) {
                float x = pxs[ppl * PSTR + j];
                float y = pys[ppl * PSTR + j];
                float z = pzs[ppl * PSTR + j];
                float cz = floorf((z - PCMINZ) * RECIPZ);
                float ctz = (cz + 0.5f) * VOXZ + PCMINZ;
                float h = fmaf(x, Ac, fmaf(y, Bc, fmaf(z, Cc, fmaf(z - ctz, s8, D))));
                acc += fmaxf(h, 0.0f);
            }
            for (int j = SLOTS; j < k; ++j) {      // ~never taken
                float4 e = ext[(size_t)(gp0 + ppl) * ECAP + (j - 1)];
                float cz = floorf((e.z - PCMINZ) * RECIPZ);
                float ctz = (cz + 0.5f) * VOXZ + PCMINZ;
                float h = fmaf(e.x, Ac, fmaf(e.y, Bc, fmaf(e.z, Cc,
                              fmaf(e.z - ctz, s8, D))));
                acc += fmaxf(h, 0.0f);
            }
            acc /= (float)k;
        }
        tileb[lane * 65 + ppl] = acc;
    }
    __syncthreads();

    // ---- phase 3: nontemporal float4 write-out (64 rows x 16 float4) ----
    int b = gp0 >> 18;                 // NSEG = 2^18
    int pbatch = gp0 & (NSEG - 1);
    size_t obase = (size_t)b * CCH * NSEG + (size_t)pbatch;
    for (int jj = 0; jj < 4; ++jj) {
        int idx = jj * 256 + t;
        int c = idx >> 4;              // channel row 0..63
        int q = idx & 15;              // float4 within row
        nt_float4 v;
        v.x = tileb[c * 65 + q * 4 + 0];
        v.y = tileb[c * 65 + q * 4 + 1];
        v.z = tileb[c * 65 + q * 4 + 2];
        v.w = tileb[c * 65 + q * 4 + 3];
        __builtin_nontemporal_store(
            v, reinterpret_cast<nt_float4*>(out + obase + (size_t)c * NSEG + q * 4));
    }
}

extern "C" void kernel_launch(void* const* d_in, const int* in_sizes, int n_in,
                              void* d_out, int out_size, void* d_ws, size_t ws_size,
                              hipStream_t stream) {
    const float* points = (const float*)d_in[0];
    const float* W      = (const float*)d_in[1];
    const float* gamma  = (const float*)d_in[2];
    const float* beta   = (const float*)d_in[3];
    const float* rmean  = (const float*)d_in[4];
    const float* rvar   = (const float*)d_in[5];
    float* out = (float*)d_out;

    int B = out_size / (CCH * NSEG);          // 2
    int N = in_sizes[0] / (3 * B);            // 100000
    int BN = B * NSEG;                        // 524288
    int total_pts = B * N;

    // workspace: cnt [BN] u32 (2 MB) + first [BN] float4 (8.4 MB)
    //          + ext [BN*15] float4 (126 MB)
    unsigned* cnt = (unsigned*)d_ws;
    float4* first = (float4*)(cnt + BN);
    float4* ext   = first + BN;

    (void)hipMemsetAsync(cnt, 0, (size_t)BN * sizeof(unsigned), stream);

    int blk = 256;
    int grd_pts = (total_pts + blk - 1) / blk;
    k1_bin<<<grd_pts, blk, 0, stream>>>(points, cnt, first, ext, B, N);
    k4_compute<<<BN / PPB, blk, 0, stream>>>(cnt, first, ext, W, gamma, beta,
                                             rmean, rvar, out);
}